// Round 7
// baseline (332.221 us; speedup 1.0000x reference)
//
#include <hip/hip_runtime.h>
#include <cstdint>
#include <cstddef>

#define B_    4
#define SQ_   4096
#define SK_   1024
#define HID_  640
#define SATD_ 768
#define NH_   10
#define HD_   64

typedef __bf16 bf16_t;
typedef __bf16 bf16x4 __attribute__((ext_vector_type(4)));
typedef __bf16 bf16x8 __attribute__((ext_vector_type(8)));
typedef float  f32x4  __attribute__((ext_vector_type(4)));
typedef unsigned short u16x8 __attribute__((ext_vector_type(8)));

static __device__ __forceinline__ unsigned short f2u(float f) {
  bf16_t b = (bf16_t)f;
  return __builtin_bit_cast(unsigned short, b);
}
static __device__ __forceinline__ float u2f(unsigned short u) {
  return (float)__builtin_bit_cast(bf16_t, u);
}
static __device__ __forceinline__ f32x4 mfma16(bf16x8 a, bf16x8 b, f32x4 c) {
  return __builtin_amdgcn_mfma_f32_16x16x32_bf16(a, b, c, 0, 0, 0);
}
static __device__ __forceinline__ void glds16(const unsigned short* g, unsigned short* l) {
  __builtin_amdgcn_global_load_lds((const __attribute__((address_space(1))) void*)g,
                                   (__attribute__((address_space(3))) void*)l, 16, 0, 0);
}

// ================= fused prep: weight transposes + bias concat + satLN + pf1 =======
__global__ __launch_bounds__(256) void k_prep(const float* __restrict__ Wq,
                                              const float* __restrict__ Wk,
                                              const float* __restrict__ Wv,
                                              const float* __restrict__ Wp2,
                                              unsigned short* __restrict__ wqT,
                                              unsigned short* __restrict__ kvT,
                                              unsigned short* __restrict__ wp2T,
                                              const float* __restrict__ bk,
                                              const float* __restrict__ bv,
                                              float* __restrict__ bias_kv,
                                              const float* __restrict__ sat,
                                              const float* __restrict__ slg,
                                              const float* __restrict__ slb,
                                              unsigned short* __restrict__ sn,
                                              const float* __restrict__ plk,
                                              const float* __restrict__ Wp1,
                                              const float* __restrict__ bp1,
                                              unsigned short* __restrict__ pf1) {
  __shared__ unsigned short tile[64 * 65];
  __shared__ float sb[8];
  const int bx = blockIdx.x, t = threadIdx.x;

  if (bx < 480) {
    int seg = bx / 120, inner = bx % 120;
    const float* W; unsigned short* D; int K;
    if (seg == 0)      { W = Wq;  D = wqT;  K = 640; }
    else if (seg == 1) { W = Wk;  D = kvT;  K = 768; }
    else if (seg == 2) { W = Wv;  D = kvT + (size_t)640 * 768; K = 768; }
    else               { W = Wp2; D = wp2T; K = 640; }
    const int ktiles = K / 64;
    int kt = inner % ktiles, ntile = inner / ktiles;
    if (ntile >= 10) return;
    const int k0 = kt * 64, n0 = ntile * 64;
    const int r = t >> 3, c8 = (t & 7) * 8;
#pragma unroll
    for (int i = 0; i < 2; i++) {
      int row = r + i * 32;
      const float* wp = W + (size_t)(k0 + row) * HID_ + n0 + c8;
      float4 a0 = *(const float4*)wp, a1 = *(const float4*)(wp + 4);
      tile[(c8 + 0) * 65 + row] = f2u(a0.x);
      tile[(c8 + 1) * 65 + row] = f2u(a0.y);
      tile[(c8 + 2) * 65 + row] = f2u(a0.z);
      tile[(c8 + 3) * 65 + row] = f2u(a0.w);
      tile[(c8 + 4) * 65 + row] = f2u(a1.x);
      tile[(c8 + 5) * 65 + row] = f2u(a1.y);
      tile[(c8 + 6) * 65 + row] = f2u(a1.z);
      tile[(c8 + 7) * 65 + row] = f2u(a1.w);
    }
    __syncthreads();
#pragma unroll
    for (int i = 0; i < 2; i++) {
      int nl = r + i * 32;
      u16x8 o;
#pragma unroll
      for (int u = 0; u < 8; u++) o[u] = tile[nl * 65 + c8 + u];
      *(u16x8*)(D + (size_t)(n0 + nl) * K + k0 + c8) = o;
    }
  } else if (bx < 485) {
    int i = (bx - 480) * 256 + t;
    if (i < HID_) bias_kv[i] = bk[i];
    else if (i < 2 * HID_) bias_kv[i] = bv[i - HID_];
  } else if (bx < 4581) {
    int r = bx - 485;
    const float* xr = sat + (size_t)r * SATD_;
    float v0 = xr[t], v1 = xr[t + 256], v2 = xr[t + 512];
    float s = v0 + v1 + v2;
    float ss = v0 * v0 + v1 * v1 + v2 * v2;
    for (int o = 32; o; o >>= 1) { s += __shfl_xor(s, o); ss += __shfl_xor(ss, o); }
    if ((t & 63) == 0) { sb[t >> 6] = s; sb[4 + (t >> 6)] = ss; }
    __syncthreads();
    s  = sb[0] + sb[1] + sb[2] + sb[3];
    ss = sb[4] + sb[5] + sb[6] + sb[7];
    float m = s * (1.f / SATD_);
    float rstd = rsqrtf(ss * (1.f / SATD_) - m * m + 1e-5f);
    unsigned short* orow = sn + (size_t)r * SATD_;
    orow[t]       = f2u((v0 - m) * rstd * slg[t]       + slb[t]);
    orow[t + 256] = f2u((v1 - m) * rstd * slg[t + 256] + slb[t + 256]);
    orow[t + 512] = f2u((v2 - m) * rstd * slg[t + 512] + slb[t + 512]);
  } else {
    int i = (bx - 4581) * 256 + t;
    int r = i / 80, c8 = (i - r * 80) * 8;
    const float* p = plk + (size_t)r * 6;
    float pv[6];
#pragma unroll
    for (int j = 0; j < 6; j++) pv[j] = p[j];
    u16x8 o;
#pragma unroll
    for (int u = 0; u < 8; u++) {
      int c = c8 + u;
      float a = bp1[c];
#pragma unroll
      for (int j = 0; j < 6; j++) a += pv[j] * Wp1[j * HID_ + c];
      o[u] = f2u(a / (1.f + __expf(-a)));
    }
    *(u16x8*)&pf1[(size_t)r * HID_ + c8] = o;
  }
}

// ================= mega-GEMM, single-barrier double-buffered K-loop (BK=32) ========
// 1D grid 1600: [0,640) z0 pf2 | [640,1280) z1 Q(+rope, f32 A via regs) | [1280,1600) z2 KV
__global__ __launch_bounds__(256) void k_gemm3(const unsigned short* __restrict__ pf1,
                                               const float* __restrict__ hidden,
                                               const unsigned short* __restrict__ sn,
                                               const unsigned short* __restrict__ wp2T,
                                               const unsigned short* __restrict__ wqT,
                                               const unsigned short* __restrict__ kvT,
                                               const float* __restrict__ bp2,
                                               const float* __restrict__ bq,
                                               const float* __restrict__ bias_kv,
                                               unsigned short* __restrict__ pf2,
                                               unsigned short* __restrict__ q_lin,
                                               unsigned short* __restrict__ k_lin,
                                               unsigned short* __restrict__ vT,
                                               const float* __restrict__ bev_xy,
                                               const float* __restrict__ sat_xy) {
  __shared__ unsigned short As[2][128 * 32];
  __shared__ unsigned short Bs[2][128 * 32];
  const int bx = blockIdx.x;
  int z, inner;
  if (bx < 640)       { z = 0; inner = bx; }
  else if (bx < 1280) { z = 1; inner = bx - 640; }
  else                { z = 2; inner = bx - 1280; }
  int bm, bn, K;
  const unsigned short* BT;
  const unsigned short* Abf = nullptr;
  const float* bias;
  {
    const int xcd = inner & 7, jj = inner >> 3;
    if (z == 2) {
      bm = ((jj / 10) * 8 + xcd) * 128;
      bn = (jj % 10) * 128;
      K = 768; BT = kvT; bias = bias_kv; Abf = sn;
    } else {
      bm = ((jj / 5) * 8 + xcd) * 128;
      bn = (jj % 5) * 128;
      K = 640;
      BT = z ? wqT : wp2T;
      bias = z ? bq : bp2;
      Abf = pf1;   // unused when z==1
    }
  }
  const int n_iter = K / 32;
  const int t = threadIdx.x, wv = t >> 6, lane = t & 63;
  const int lc = lane & 15, quad = lane >> 4;
  const int wm = (wv >> 1) * 64, wn = (wv & 1) * 64;
  f32x4 acc[4][4];
  f32x4 zero = {0.f, 0.f, 0.f, 0.f};
#pragma unroll
  for (int i = 0; i < 4; i++)
#pragma unroll
    for (int j = 0; j < 4; j++) acc[i][j] = zero;
  // glds staging: wave wv covers rows wv*32 + i*16 + (lane>>2), col chunk (lane&3)*8
  const int grow = wv * 32 + (lane >> 2);
  const int gc8 = (lane & 3) * 8;
  // f32 reg staging: rows t>>2 + i*64, cols (t&3)*8
  const int frow = t >> 2, fc8 = (t & 3) * 8;
  float4 ar[2][2];

  // ---- prologue: tile 0 ----
  if (z != 1) {
#pragma unroll
    for (int i = 0; i < 2; i++)
      glds16(Abf + (size_t)(bm + grow + i * 16) * K + gc8, &As[0][(wv * 32 + i * 16) * 32]);
  } else {
#pragma unroll
    for (int i = 0; i < 2; i++) {
      const float* ap = hidden + (size_t)(bm + frow + i * 64) * K + fc8;
      ar[i][0] = *(const float4*)ap;
      ar[i][1] = *(const float4*)(ap + 4);
    }
  }
#pragma unroll
  for (int i = 0; i < 2; i++)
    glds16(BT + (size_t)(bn + grow + i * 16) * K + gc8, &Bs[0][(wv * 32 + i * 16) * 32]);

  for (int ki = 0; ki < n_iter; ki++) {
    const int cur = ki & 1;
    const int k1 = (ki + 1) * 32;
    if (z == 1) {
      // convert + deposit current A tile (waits on its global loads), then barrier
#pragma unroll
      for (int i = 0; i < 2; i++) {
        u16x8 u = { f2u(ar[i][0].x), f2u(ar[i][0].y), f2u(ar[i][0].z), f2u(ar[i][0].w),
                    f2u(ar[i][1].x), f2u(ar[i][1].y), f2u(ar[i][1].z), f2u(ar[i][1].w) };
        *(u16x8*)&As[cur][(frow + i * 64) * 32 + fc8] = u;
      }
    }
    __syncthreads();   // drains prev glds (full compute phase in flight) + LDS writes
    if (ki + 1 < n_iter) {
      if (z != 1) {
#pragma unroll
        for (int i = 0; i < 2; i++)
          glds16(Abf + (size_t)(bm + grow + i * 16) * K + k1 + gc8,
                 &As[1 - cur][(wv * 32 + i * 16) * 32]);
      } else {
#pragma unroll
        for (int i = 0; i < 2; i++) {
          const float* ap = hidden + (size_t)(bm + frow + i * 64) * K + k1 + fc8;
          ar[i][0] = *(const float4*)ap;
          ar[i][1] = *(const float4*)(ap + 4);
        }
      }
#pragma unroll
      for (int i = 0; i < 2; i++)
        glds16(BT + (size_t)(bn + grow + i * 16) * K + k1 + gc8,
               &Bs[1 - cur][(wv * 32 + i * 16) * 32]);
    }
    bf16x8 af[4], bfr[4];
#pragma unroll
    for (int mt = 0; mt < 4; mt++) af[mt]  = *(const bf16x8*)&As[cur][(wm + mt * 16 + lc) * 32 + quad * 8];
#pragma unroll
    for (int nt = 0; nt < 4; nt++) bfr[nt] = *(const bf16x8*)&Bs[cur][(wn + nt * 16 + lc) * 32 + quad * 8];
#pragma unroll
    for (int mt = 0; mt < 4; mt++)
#pragma unroll
      for (int nt = 0; nt < 4; nt++) acc[mt][nt] = mfma16(af[mt], bfr[nt], acc[mt][nt]);
  }

  float bsv[4];
#pragma unroll
  for (int nt = 0; nt < 4; nt++) bsv[nt] = bias[bn + wn + nt * 16 + lc];
  const float inv = __builtin_amdgcn_exp2f(-(float)lc * 0.8304820237218407f);

  if (z == 0) {
#pragma unroll
    for (int mt = 0; mt < 4; mt++) {
      int row = bm + wm + mt * 16 + quad * 4;
#pragma unroll
      for (int r = 0; r < 4; r++) {
        unsigned short* crow = pf2 + (size_t)(row + r) * HID_ + bn + wn + lc;
        crow[0]  = f2u(acc[mt][0][r] + bsv[0]);
        crow[16] = f2u(acc[mt][1][r] + bsv[1]);
        crow[32] = f2u(acc[mt][2][r] + bsv[2]);
        crow[48] = f2u(acc[mt][3][r] + bsv[3]);
      }
    }
  } else if (z == 1) {
    const float qscale = 0.18033688011112042f;   // 0.125 * log2(e)
#pragma unroll
    for (int mt = 0; mt < 4; mt++) {
      int row = bm + wm + mt * 16 + quad * 4;
#pragma unroll
      for (int r = 0; r < 4; r++) {
        unsigned short* crow = q_lin + (size_t)(row + r) * HID_ + bn + wn + lc;
        float v0 = acc[mt][0][r] + bsv[0];
        float v1 = acc[mt][1][r] + bsv[1];
        float v2 = acc[mt][2][r] + bsv[2];
        float v3 = acc[mt][3][r] + bsv[3];
        float2 xy = *(const float2*)&bev_xy[(size_t)(row + r) * 2];
        float s0, c0, s1, c1;
        __sincosf(xy.x * inv, &s0, &c0);
        __sincosf(xy.y * inv, &s1, &c1);
        crow[0]  = f2u((v0 * c0 - v2 * s0) * qscale);
        crow[32] = f2u((v0 * s0 + v2 * c0) * qscale);
        crow[16] = f2u((v1 * c1 - v3 * s1) * qscale);
        crow[48] = f2u((v1 * s1 + v3 * c1) * qscale);
      }
    }
  } else if (bn < HID_) {
#pragma unroll
    for (int mt = 0; mt < 4; mt++) {
      int row = bm + wm + mt * 16 + quad * 4;
#pragma unroll
      for (int r = 0; r < 4; r++) {
        unsigned short* crow = k_lin + (size_t)(row + r) * HID_ + bn + wn + lc;
        float v0 = acc[mt][0][r] + bsv[0];
        float v1 = acc[mt][1][r] + bsv[1];
        float v2 = acc[mt][2][r] + bsv[2];
        float v3 = acc[mt][3][r] + bsv[3];
        float2 xy = *(const float2*)&sat_xy[(size_t)(row + r) * 2];
        float s0, c0, s1, c1;
        __sincosf(xy.x * inv, &s0, &c0);
        __sincosf(xy.y * inv, &s1, &c1);
        crow[0]  = f2u(v0 * c0 - v2 * s0);
        crow[32] = f2u(v0 * s0 + v2 * c0);
        crow[16] = f2u(v1 * c1 - v3 * s1);
        crow[48] = f2u(v1 * s1 + v3 * c1);
      }
    }
  } else {
#pragma unroll
    for (int mt = 0; mt < 4; mt++) {
      int row0 = bm + wm + mt * 16 + quad * 4;
      int bidx = row0 >> 10, key0 = row0 & 1023;
#pragma unroll
      for (int nt = 0; nt < 4; nt++) {
        int d = bn - HID_ + wn + nt * 16 + lc;
        bf16x4 v;
#pragma unroll
        for (int r = 0; r < 4; r++) v[r] = (bf16_t)(acc[mt][nt][r] + bsv[nt]);
        *(bf16x4*)(vT + ((size_t)(bidx * HID_ + d) << 10) + key0) = v;
      }
    }
  }
}

// ================= gate: one wave per row =================
__global__ __launch_bounds__(256) void k_gate(const float* __restrict__ hid,
                                              const unsigned short* __restrict__ pf2,
                                              const float* __restrict__ g,
                                              const float* __restrict__ be,
                                              const float* __restrict__ Wg,
                                              const float* __restrict__ bg,
                                              const float* __restrict__ vm,
                                              float* __restrict__ gate_buf,
                                              float* __restrict__ lg_buf) {
  const int row = blockIdx.x * 4 + (threadIdx.x >> 6);
  const int lane = threadIdx.x & 63;
  const float* hr = hid + (size_t)row * HID_;
  const unsigned short* pr = pf2 + (size_t)row * HID_;
  float x[10];
  float s = 0.f, ss = 0.f;
#pragma unroll
  for (int u = 0; u < 10; u++) {
    int c = u * 64 + lane;
    float v = hr[c] + u2f(pr[c]);
    x[u] = v; s += v; ss += v * v;
  }
#pragma unroll
  for (int o = 32; o; o >>= 1) { s += __shfl_xor(s, o); ss += __shfl_xor(ss, o); }
  float m = s * (1.f / HID_);
  float rstd = rsqrtf(ss * (1.f / HID_) - m * m + 1e-5f);
  float d = 0.f;
#pragma unroll
  for (int u = 0; u < 10; u++) {
    int c = u * 64 + lane;
    d += ((x[u] - m) * rstd * g[c] + be[c]) * Wg[c];
  }
#pragma unroll
  for (int o = 32; o; o >>= 1) d += __shfl_xor(d, o);
  if (lane == 0) {
    float gate = 1.f / (1.f + __expf(-(d + bg[0])));
    float v = vm[row];
    gate_buf[row] = (v > 0.5f) ? gate : 0.f;
    lg_buf[row]   = (v > 0.5f) ? 0.f : gate;
  }
}

// ================= attention: 256q/block, 64q/wave, swizzled K/V, reg prefetch ======
__global__ __launch_bounds__(256) void k_attn(const unsigned short* __restrict__ q_lin,
                                              const unsigned short* __restrict__ k_lin,
                                              const unsigned short* __restrict__ vT,
                                              const float* __restrict__ gate_buf,
                                              float* __restrict__ out) {
  __shared__ unsigned short Ks[64 * 64];      // swizzled: row*64 + (chunk^(row&7))*8
  __shared__ unsigned short Vt[64 * 64];      // swizzled
  __shared__ unsigned short Pt[4][64 * 72];   // per wave [q][key], stride 72
  const int qb = blockIdx.x * 256;
  const int bh = blockIdx.y;
  const int b = bh / NH_, h = bh - b * NH_;
  const int t = threadIdx.x, wv = t >> 6, lane = t & 63;
  const int lc = lane & 15, quad = lane >> 4;
  unsigned short* myPt = &Pt[wv][0];

  // Q frags: q = qb + wv*64 + g*16 + lc
  const unsigned short* qbase = q_lin + (size_t)(b * SQ_ + qb + wv * 64 + lc) * HID_ + h * HD_;
  bf16x8 qf[4][2];
#pragma unroll
  for (int g = 0; g < 4; g++) {
    qf[g][0] = *(const bf16x8*)(qbase + (size_t)g * 16 * HID_ + quad * 8);
    qf[g][1] = *(const bf16x8*)(qbase + (size_t)g * 16 * HID_ + 32 + quad * 8);
  }
  f32x4 zero = {0.f, 0.f, 0.f, 0.f};
  f32x4 O[4][4];
#pragma unroll
  for (int g = 0; g < 4; g++)
#pragma unroll
    for (int dt = 0; dt < 4; dt++) O[g][dt] = zero;
  float l_run[4] = {0.f, 0.f, 0.f, 0.f};

  const unsigned short* Kg = k_lin + (size_t)b * SK_ * HID_ + h * HD_;
  const unsigned short* Vg = vT + ((size_t)b * HID_ + h * HD_) * SK_;
  const int srow = t >> 3, sc = t & 7;   // stage: row srow(+32), chunk sc

  u16x8 kpre[2], vpre[2];
#pragma unroll
  for (int i = 0; i < 2; i++) {
    kpre[i] = *(const u16x8*)(Kg + (size_t)(srow + i * 32) * HID_ + sc * 8);
    vpre[i] = *(const u16x8*)(Vg + (size_t)(srow + i * 32) * SK_ + sc * 8);
  }

  for (int kc = 0; kc < SK_; kc += 64) {
    __syncthreads();
#pragma unroll
    for (int i = 0; i < 2; i++) {
      int row = srow + i * 32;
      int off = row * 64 + ((sc ^ (row & 7)) << 3);
      *(u16x8*)&Ks[off] = kpre[i];
      *(u16x8*)&Vt[off] = vpre[i];
    }
    __syncthreads();
    if (kc + 64 < SK_) {
#pragma unroll
      for (int i = 0; i < 2; i++) {
        kpre[i] = *(const u16x8*)(Kg + (size_t)(kc + 64 + srow + i * 32) * HID_ + sc * 8);
        vpre[i] = *(const u16x8*)(Vg + (size_t)(srow + i * 32) * SK_ + kc + 64 + sc * 8);
      }
    }

    // QK + softmax per q-group (exp2 domain, no-max)
#pragma unroll
    for (int g = 0; g < 4; g++) {
      f32x4 ST[4];
#pragma unroll
      for (int kt = 0; kt < 4; kt++) {
        int key = kt * 16 + lc;
        bf16x8 ka0 = *(const bf16x8*)&Ks[key * 64 + ((quad ^ (key & 7)) << 3)];
        bf16x8 ka1 = *(const bf16x8*)&Ks[key * 64 + (((quad + 4) ^ (key & 7)) << 3)];
        ST[kt] = mfma16(ka1, qf[g][1], mfma16(ka0, qf[g][0], zero));
      }
      float rs = 0.f;
#pragma unroll
      for (int kt = 0; kt < 4; kt++) {
        bf16x4 pk;
#pragma unroll
        for (int r = 0; r < 4; r++) {
          float p = __builtin_amdgcn_exp2f(ST[kt][r]);
          rs += p;
          pk[r] = (bf16_t)p;
        }
        *(bf16x4*)&myPt[(g * 16 + lc) * 72 + kt * 16 + quad * 4] = pk;
      }
      rs += __shfl_xor(rs, 16);
      rs += __shfl_xor(rs, 32);
      l_run[g] += rs;
    }
    // PV
#pragma unroll
    for (int ks = 0; ks < 2; ks++) {
      bf16x8 va[4];
#pragma unroll
      for (int dt = 0; dt < 4; dt++) {
        int d = dt * 16 + lc;
        va[dt] = *(const bf16x8*)&Vt[d * 64 + (((ks * 4 + quad) ^ (d & 7)) << 3)];
      }
#pragma unroll
      for (int g = 0; g < 4; g++) {
        bf16x8 pb = *(const bf16x8*)&myPt[(g * 16 + lc) * 72 + ks * 32 + quad * 8];
#pragma unroll
        for (int dt = 0; dt < 4; dt++)
          O[g][dt] = mfma16(va[dt], pb, O[g][dt]);
      }
    }
  }

#pragma unroll
  for (int g = 0; g < 4; g++) {
    int rg = b * SQ_ + qb + wv * 64 + g * 16 + lc;
    float gv = gate_buf[rg] / l_run[g];
    float* orow = out + (size_t)rg * HID_ + h * HD_;
#pragma unroll
    for (int dt = 0; dt < 4; dt++) {
      f32x4 o4 = O[g][dt] * gv;
      *(f32x4*)&orow[dt * 16 + quad * 4] = o4;
    }
  }
}

// ================= loss reduction =================
__global__ __launch_bounds__(256) void k_loss(const float* __restrict__ lg,
                                              const float* __restrict__ vm,
                                              float* __restrict__ out_loss) {
  int t = threadIdx.x;
  float s = 0.f, cnt = 0.f;
  for (int i = t; i < B_ * SQ_; i += 256) {
    s += lg[i];
    cnt += (vm[i] > 0.5f) ? 0.f : 1.f;
  }
  __shared__ float sb[8];
  for (int o = 32; o; o >>= 1) { s += __shfl_xor(s, o); cnt += __shfl_xor(cnt, o); }
  if ((t & 63) == 0) { sb[t >> 6] = s; sb[4 + (t >> 6)] = cnt; }
  __syncthreads();
  if (t == 0) {
    s   = sb[0] + sb[1] + sb[2] + sb[3];
    cnt = sb[4] + sb[5] + sb[6] + sb[7];
    out_loss[0] = s / fmaxf(cnt, 1.f) * 0.05f;
  }
}

extern "C" void kernel_launch(void* const* d_in, const int* in_sizes, int n_in,
                              void* d_out, int out_size, void* d_ws, size_t ws_size,
                              hipStream_t stream) {
  (void)in_sizes; (void)n_in; (void)out_size; (void)ws_size;
  const float* hidden = (const float*)d_in[0];
  const float* sat    = (const float*)d_in[1];
  const float* sat_xy = (const float*)d_in[2];
  const float* bev_xy = (const float*)d_in[3];
  const float* plk    = (const float*)d_in[4];
  const float* vm     = (const float*)d_in[5];
  const float* Wq     = (const float*)d_in[6];
  const float* bq     = (const float*)d_in[7];
  const float* slg    = (const float*)d_in[8];
  const float* slb    = (const float*)d_in[9];
  const float* Wk     = (const float*)d_in[10];
  const float* bk     = (const float*)d_in[11];
  const float* Wv     = (const float*)d_in[12];
  const float* bv     = (const float*)d_in[13];
  const float* Wp1    = (const float*)d_in[14];
  const float* bp1    = (const float*)d_in[15];
  const float* Wp2    = (const float*)d_in[16];
  const float* bp2    = (const float*)d_in[17];
  const float* glg    = (const float*)d_in[18];
  const float* glb    = (const float*)d_in[19];
  const float* Wg     = (const float*)d_in[20];
  const float* bg     = (const float*)d_in[21];
  float* out = (float*)d_out;

  char* ws = (char*)d_ws;
  size_t off = 0;
  auto alloc = [&](size_t bytes) -> char* {
    char* p = ws + off;
    off += (bytes + 255) & ~(size_t)255;
    return p;
  };
  // pf2 staged in d_out (fully overwritten later by k_attn/k_loss)
  unsigned short* pf2   = (unsigned short*)d_out;
  unsigned short* pf1   = (unsigned short*)alloc((size_t)16384 * 640 * 2);
  unsigned short* q_lin = (unsigned short*)alloc((size_t)16384 * 640 * 2);
  unsigned short* k_lin = (unsigned short*)alloc((size_t)4096 * 640 * 2);
  unsigned short* vT    = (unsigned short*)alloc((size_t)B_ * HID_ * SK_ * 2);
  unsigned short* sn    = (unsigned short*)alloc((size_t)4096 * 768 * 2);
  unsigned short* wqT   = (unsigned short*)alloc((size_t)640 * 640 * 2);
  unsigned short* kvT   = (unsigned short*)alloc((size_t)1280 * 768 * 2);
  unsigned short* wp2T  = (unsigned short*)alloc((size_t)640 * 640 * 2);
  float* bias_kv  = (float*)alloc(1280 * 4);
  float* gate_buf = (float*)alloc(16384 * 4);
  float* lg_buf   = (float*)alloc(16384 * 4);

  // 1) fused prep
  k_prep<<<9701, 256, 0, stream>>>(Wq, Wk, Wv, Wp2, wqT, kvT, wp2T,
                                   bk, bv, bias_kv,
                                   sat, slg, slb, sn,
                                   plk, Wp1, bp1, pf1);

  // 2) mega-GEMM (1600 blocks, 1D)
  k_gemm3<<<1600, 256, 0, stream>>>(pf1, hidden, sn, wp2T, wqT, kvT,
                                    bp2, bq, bias_kv,
                                    pf2, q_lin, k_lin, vT, bev_xy, sat_xy);

  // 3) gate
  k_gate<<<4096, 256, 0, stream>>>(hidden, pf2, glg, glb, Wg, bg, vm, gate_buf, lg_buf);

  // 4) attention (256 q per block)
  {
    dim3 g(SQ_ / 256, B_ * NH_);
    k_attn<<<g, 256, 0, stream>>>(q_lin, k_lin, vT, gate_buf, out);
  }
  // 5) loss
  k_loss<<<1, 256, 0, stream>>>(lg_buf, vm, out + (size_t)B_ * SQ_ * HID_);
}